// Round 4
// baseline (218.923 us; speedup 1.0000x reference)
//
#include <hip/hip_runtime.h>
#include <hip/hip_bf16.h>

#define BB 8
#define NN 2048
#define CC 320
#define CQ 64

typedef __attribute__((ext_vector_type(8)))  short bf16x8;
typedef __attribute__((ext_vector_type(4)))  float f32x4;
typedef __attribute__((ext_vector_type(16))) float f32x16;
typedef __attribute__((ext_vector_type(4)))  unsigned short us4;
typedef __attribute__((ext_vector_type(8)))  unsigned short us8;
typedef unsigned short u16;

static __device__ __forceinline__ u16 f2b(float f) {
  unsigned u = __builtin_bit_cast(unsigned, f);
  unsigned r = (u + 0x7FFFu + ((u >> 16) & 1u)) >> 16;
  return (u16)r;
}

static __device__ __forceinline__ f32x16 zero16() {
  f32x16 v = {0,0,0,0, 0,0,0,0, 0,0,0,0, 0,0,0,0};
  return v;
}
static __device__ __forceinline__ f32x4 zero4() {
  f32x4 v = {0,0,0,0};
  return v;
}

// ---------------------------------------------------------------------------
// K0a: x fp32 -> xb bf16. grid 5120 x 256
// ---------------------------------------------------------------------------
__global__ __launch_bounds__(256) void cvt_x(const float* __restrict__ x,
                                             u16* __restrict__ xb) {
  const size_t i = (size_t)blockIdx.x * 256 + threadIdx.x;
  float4 v = *(const float4*)(x + i * 4);
  us4 o;
  o.x = f2b(v.x); o.y = f2b(v.y); o.z = f2b(v.z); o.w = f2b(v.w);
  *(us4*)(xb + i * 4) = o;
}

// ---------------------------------------------------------------------------
// K0b: Wq/Wk/Wv fp32 -> concat Wb[448][320] bf16. grid 140 x 256
// ---------------------------------------------------------------------------
__global__ __launch_bounds__(256) void cvt_w(const float* __restrict__ Wq,
                                             const float* __restrict__ Wk,
                                             const float* __restrict__ Wv,
                                             u16* __restrict__ Wb) {
  const int i = blockIdx.x * 256 + threadIdx.x;
  const int idx4 = i * 4;
  const int row = idx4 / CC;
  const int col = idx4 - row * CC;
  const float* src = (row < 64) ? (Wq + (size_t)row * CC)
                   : (row < 128) ? (Wk + (size_t)(row - 64) * CC)
                                 : (Wv + (size_t)(row - 128) * CC);
  float4 v = *(const float4*)(src + col);
  us4 o;
  o.x = f2b(v.x); o.y = f2b(v.y); o.z = f2b(v.z); o.w = f2b(v.w);
  *(us4*)(Wb + (size_t)row * CC + col) = o;
}

// ---------------------------------------------------------------------------
// K1: QKV GEMM with explicit load prefetch. grid (7, 128)
// ---------------------------------------------------------------------------
__global__ __launch_bounds__(256) void gemm_qkv(
    const u16* __restrict__ xb, const u16* __restrict__ Wb,
    const float* __restrict__ bq, const float* __restrict__ bk,
    const float* __restrict__ bv,
    u16* __restrict__ Qb, u16* __restrict__ Kb, u16* __restrict__ Vtmp) {
  const int tid = threadIdx.x;
  const int lane = tid & 63, wid = tid >> 6;
  const int r = lane & 31, h = lane >> 5;
  const int m0 = blockIdx.y * 128 + wid * 32;
  const int col0 = blockIdx.x * 64;

  f32x16 acc0 = zero16(), acc1 = zero16();
  const u16* xrow = xb + (size_t)(m0 + r) * CC + h * 8;
  const u16* w0 = Wb + (size_t)(col0 + r) * CC + h * 8;
  const u16* w1 = w0 + 32 * CC;

  bf16x8 a   = *(const bf16x8*)(xrow);
  bf16x8 b0v = *(const bf16x8*)(w0);
  bf16x8 b1v = *(const bf16x8*)(w1);
#pragma unroll 1
  for (int ks = 0; ks < 20; ++ks) {
    bf16x8 na, nb0, nb1;
    if (ks < 19) {
      na  = *(const bf16x8*)(xrow + (ks + 1) * 16);
      nb0 = *(const bf16x8*)(w0 + (ks + 1) * 16);
      nb1 = *(const bf16x8*)(w1 + (ks + 1) * 16);
    }
    acc0 = __builtin_amdgcn_mfma_f32_32x32x16_bf16(a, b0v, acc0, 0, 0, 0);
    acc1 = __builtin_amdgcn_mfma_f32_32x32x16_bf16(a, b1v, acc1, 0, 0, 0);
    a = na; b0v = nb0; b1v = nb1;
  }

#pragma unroll
  for (int nt = 0; nt < 2; ++nt) {
    const int col = col0 + nt * 32 + r;
    const float bias = (col < 64) ? bq[col] : (col < 128) ? bk[col - 64] : bv[col - 128];
#pragma unroll
    for (int reg = 0; reg < 16; ++reg) {
      const int row = m0 + (reg & 3) + 8 * (reg >> 2) + 4 * h;
      const float v = (nt ? acc1[reg] : acc0[reg]) + bias;
      const u16 s = f2b(v);
      if (col < 64)        Qb[(size_t)row * CQ + col] = s;
      else if (col < 128)  Kb[(size_t)row * CQ + (col - 64)] = s;
      else                 Vtmp[(size_t)row * CC + (col - 128)] = s;
    }
  }
}

// ---------------------------------------------------------------------------
// K2: transpose Vtmp[16384][320] -> Vt[8][320][2048] (bf16). grid (5, 256)
// ---------------------------------------------------------------------------
__global__ __launch_bounds__(256) void vtrans(const u16* __restrict__ Vtmp,
                                              u16* __restrict__ Vt) {
  __shared__ u16 L[64][72];
  const int t = threadIdx.x;
  const int c0 = blockIdx.x * 64;
  const int p0 = blockIdx.y * 64;
  const int b = p0 >> 11;
  const int pr = t >> 3, cc = (t & 7) * 8;
#pragma unroll
  for (int hh = 0; hh < 2; ++hh) {
    const int p = pr + hh * 32;
    us8 v = *(const us8*)(Vtmp + (size_t)(p0 + p) * CC + c0 + cc);
#pragma unroll
    for (int e = 0; e < 8; ++e) L[p][cc + e] = v[e];
  }
  __syncthreads();
  const int cl = t >> 3, pp = (t & 7) * 8;
#pragma unroll
  for (int hh = 0; hh < 2; ++hh) {
    const int c = cl + hh * 32;
    us8 o;
#pragma unroll
    for (int e = 0; e < 8; ++e) o[e] = L[pp + e][c];
    *(us8*)(Vt + (((size_t)(b * CC + c0 + c)) << 11) + (p0 & 2047) + pp) = o;
  }
}

// ---------------------------------------------------------------------------
// K3: row sums with load prefetch. grid 256
// ---------------------------------------------------------------------------
__global__ __launch_bounds__(256) void row_stats(
    const u16* __restrict__ Qb, const u16* __restrict__ Kb,
    float* __restrict__ rowinv) {
  __shared__ float Sp[4][64];
  const int tid = threadIdx.x;
  const int lane = tid & 63, wid = tid >> 6;
  const int rl = lane & 15, hq = lane >> 4;
  const int bid = blockIdx.x;
  const int batch = bid & 7;
  const int r0g = batch * NN + (bid >> 3) * 64;

  bf16x8 af[4][2];
#pragma unroll
  for (int mt = 0; mt < 4; ++mt)
#pragma unroll
    for (int qs = 0; qs < 2; ++qs)
      af[mt][qs] = *(const bf16x8*)(Qb + (size_t)(r0g + mt * 16 + rl) * CQ + qs * 32 + hq * 8);

  float S[4][4];
#pragma unroll
  for (int mt = 0; mt < 4; ++mt)
#pragma unroll
    for (int rr = 0; rr < 4; ++rr) S[mt][rr] = 0.f;

  const int mstart = batch * NN + wid * 512;
  const u16* kr = Kb + (size_t)(mstart + rl) * CQ + hq * 8;
  bf16x8 c0 = *(const bf16x8*)(kr);
  bf16x8 c1 = *(const bf16x8*)(kr + 32);
#pragma unroll 1
  for (int ms = 0; ms < 32; ++ms) {
    bf16x8 n0, n1;
    if (ms < 31) {
      n0 = *(const bf16x8*)(kr + 16 * CQ);
      n1 = *(const bf16x8*)(kr + 16 * CQ + 32);
    }
#pragma unroll
    for (int mt = 0; mt < 4; ++mt) {
      f32x4 e = zero4();
      e = __builtin_amdgcn_mfma_f32_16x16x32_bf16(af[mt][0], c0, e, 0, 0, 0);
      e = __builtin_amdgcn_mfma_f32_16x16x32_bf16(af[mt][1], c1, e, 0, 0, 0);
#pragma unroll
      for (int rr = 0; rr < 4; ++rr) S[mt][rr] += __expf(e[rr] - 30.f);
    }
    c0 = n0; c1 = n1; kr += 16 * CQ;
  }

#pragma unroll
  for (int d = 1; d < 16; d <<= 1)
#pragma unroll
    for (int mt = 0; mt < 4; ++mt)
#pragma unroll
      for (int rr = 0; rr < 4; ++rr) S[mt][rr] += __shfl_xor(S[mt][rr], d, 64);

  if (rl == 0) {
#pragma unroll
    for (int mt = 0; mt < 4; ++mt)
#pragma unroll
      for (int rr = 0; rr < 4; ++rr) Sp[wid][mt * 16 + hq * 4 + rr] = S[mt][rr];
  }
  __syncthreads();
  if (tid < 64) {
    const float s = Sp[0][tid] + Sp[1][tid] + Sp[2][tid] + Sp[3][tid];
    rowinv[r0g + tid] = 1.0f / s;
  }
}

// ---------------------------------------------------------------------------
// K4: attention output, pipelined, round-2 wave partition (correct).
// Block = 64n x 320c, 4 waves: wn = wid>>1 (Et n-half AND PV n-tile),
// wc = wid&1 (Et k-half AND PV c-half). Each wave's PV: 32n x 160c x FULL
// 64k -> every output element owned by exactly one wave.
// Per k-tile: Et quadrant (32x32x16 MFMA, K-frags held) -> exp -> Pt LDS
// (double-buffered, XOR-swizzled); PV B-frags direct from L2-resident Vt.
// Pipeline: Et(t+1) -> PV(t) -> one barrier per iter.
// grid 256, batch = bid&7 pins each batch's Vt/Qb/Kb slice to one XCD L2.
// ---------------------------------------------------------------------------
__global__ __launch_bounds__(256, 1) void attn(
    const u16* __restrict__ Qb, const u16* __restrict__ Kb,
    const u16* __restrict__ Vt, const float* __restrict__ rowinv,
    const float* __restrict__ x, const float* __restrict__ gamma,
    float* __restrict__ out) {
  __shared__ __align__(16) u16 PtU[2][64 * 64];
  const int tid = threadIdx.x;
  const int lane = tid & 63, wid = tid >> 6;
  const int wn = wid >> 1;   // n-half: Et A-rows and PV output rows
  const int wc = wid & 1;    // Et k-half; PV c-half
  const int r = lane & 31, h = lane >> 5;
  const int b = blockIdx.x & 7;
  const int n0 = (blockIdx.x >> 3) * 64;

  // held A-frags for Et: K rows of this wave's n-half
  bf16x8 kf[4];
  {
    const u16* krow = Kb + (size_t)(b * NN + n0 + wn * 32 + r) * CQ + h * 8;
#pragma unroll
    for (int qs = 0; qs < 4; ++qs) kf[qs] = *(const bf16x8*)(krow + qs * 16);
  }

  f32x16 acc[5];
#pragma unroll
  for (int n = 0; n < 5; ++n) acc[n] = zero16();

  const u16* qbase = Qb + (size_t)(b * NN + wc * 32 + r) * CQ + h * 8;
  const float* rbase = rowinv + b * NN + wc * 32 + r;
  const u16* vrow = Vt + (((size_t)(b * CC + wc * 160 + r)) << 11) + h * 8;
  const int kk = wc * 32 + r;
  const int na = wn * 32 + r;
  char* Pt0 = (char*)&PtU[0][0];

#define ET_STEP(T, BUF) do {                                                   \
    const int k0_ = (T) * 64;                                                  \
    f32x16 e_ = zero16();                                                      \
    const u16* q0_ = qbase + (size_t)k0_ * CQ;                                 \
    _Pragma("unroll")                                                          \
    for (int qs = 0; qs < 4; ++qs) {                                           \
      bf16x8 qf_ = *(const bf16x8*)(q0_ + qs * 16);                            \
      e_ = __builtin_amdgcn_mfma_f32_32x32x16_bf16(kf[qs], qf_, e_, 0, 0, 0);  \
    }                                                                          \
    const float inv_ = rbase[k0_];                                             \
    _Pragma("unroll")                                                          \
    for (int reg = 0; reg < 16; ++reg) {                                       \
      const int nl_ = wn * 32 + (reg & 3) + 8 * (reg >> 2) + 4 * h;            \
      const float p_ = __expf(e_[reg] - 30.f) * inv_;                          \
      *(u16*)(Pt0 + (BUF) * 8192 + nl_ * 128 +                                 \
              ((((kk >> 3) ^ (nl_ & 7)) << 4)) + (kk & 7) * 2) = f2b(p_);      \
    }                                                                          \
  } while (0)

#define PV_STEP(T, BUF) do {                                                   \
    const int k0_ = (T) * 64;                                                  \
    _Pragma("unroll")                                                          \
    for (int ks = 0; ks < 4; ++ks) {                                           \
      const int ch_ = ks * 2 + h;                                              \
      bf16x8 pa = *(const bf16x8*)(Pt0 + (BUF) * 8192 + na * 128 +             \
                                   ((ch_ ^ (na & 7)) << 4));                   \
      _Pragma("unroll")                                                        \
      for (int nt = 0; nt < 5; ++nt) {                                         \
        bf16x8 vb = *(const bf16x8*)(vrow + (((size_t)(nt * 32)) << 11) +      \
                                     k0_ + ks * 16);                           \
        acc[nt] = __builtin_amdgcn_mfma_f32_32x32x16_bf16(pa, vb, acc[nt], 0, 0, 0); \
      }                                                                        \
    }                                                                          \
  } while (0)

  ET_STEP(0, 0);
  __syncthreads();
#pragma unroll 1
  for (int t = 0; t < 31; ++t) {
    ET_STEP(t + 1, (t + 1) & 1);
    PV_STEP(t, t & 1);
    __syncthreads();
  }
  PV_STEP(31, 1);

#undef ET_STEP
#undef PV_STEP

  const float g = gamma[0];
#pragma unroll
  for (int reg = 0; reg < 16; ++reg) {
    const int nl = n0 + wn * 32 + (reg & 3) + 8 * (reg >> 2) + 4 * h;
    const size_t rowb = ((size_t)(b * NN) + nl) * CC + wc * 160 + r;
#pragma unroll
    for (int nt = 0; nt < 5; ++nt) {
      const size_t idx = rowb + (size_t)(nt * 32);
      out[idx] = g * acc[nt][reg] + x[idx];
    }
  }
}

extern "C" void kernel_launch(void* const* d_in, const int* in_sizes, int n_in,
                              void* d_out, int out_size, void* d_ws, size_t ws_size,
                              hipStream_t stream) {
  const float* x     = (const float*)d_in[0];
  const float* Wq    = (const float*)d_in[1];
  const float* bq    = (const float*)d_in[2];
  const float* Wk    = (const float*)d_in[3];
  const float* bk    = (const float*)d_in[4];
  const float* Wv    = (const float*)d_in[5];
  const float* bv    = (const float*)d_in[6];
  const float* gamma = (const float*)d_in[7];
  float* out = (float*)d_out;

  char* w = (char*)d_ws;
  u16* xb     = (u16*)(w);                         // 16384*320
  u16* Wb     = (u16*)(w + 10485760);              // 448*320
  u16* Qb     = (u16*)(w + 10772480);              // 16384*64
  u16* Kb     = (u16*)(w + 12869632);              // 16384*64
  u16* Vtmp   = (u16*)(w + 14966784);              // 16384*320
  u16* Vt     = (u16*)(w + 25452544);              // 8*320*2048
  float* rinv = (float*)(w + 35938304);            // 16384

  cvt_x<<<5120, 256, 0, stream>>>(x, xb);
  cvt_w<<<140, 256, 0, stream>>>(Wq, Wk, Wv, Wb);
  gemm_qkv<<<dim3(7, 128), 256, 0, stream>>>(xb, Wb, bq, bk, bv, Qb, Kb, Vtmp);
  vtrans<<<dim3(5, 256), 256, 0, stream>>>(Vtmp, Vt);
  row_stats<<<256, 256, 0, stream>>>(Qb, Kb, rinv);
  attn<<<256, 256, 0, stream>>>(Qb, Kb, Vt, rinv, x, gamma, out);
}

// Round 5
// 185.700 us; speedup vs baseline: 1.1789x; 1.1789x over previous
//
#include <hip/hip_runtime.h>
#include <hip/hip_bf16.h>

#define BB 8
#define NN 2048
#define CC 320
#define CQ 64

typedef __attribute__((ext_vector_type(8)))  short bf16x8;
typedef __attribute__((ext_vector_type(4)))  float f32x4;
typedef __attribute__((ext_vector_type(16))) float f32x16;
typedef __attribute__((ext_vector_type(4)))  unsigned short us4;
typedef __attribute__((ext_vector_type(8)))  unsigned short us8;
typedef unsigned short u16;

static __device__ __forceinline__ u16 f2b(float f) {
  unsigned u = __builtin_bit_cast(unsigned, f);
  unsigned r = (u + 0x7FFFu + ((u >> 16) & 1u)) >> 16;
  return (u16)r;
}
static __device__ __forceinline__ float b2f(u16 s) {
  unsigned u = ((unsigned)s) << 16;
  return __builtin_bit_cast(float, u);
}

static __device__ __forceinline__ f32x16 zero16() {
  f32x16 v = {0,0,0,0, 0,0,0,0, 0,0,0,0, 0,0,0,0};
  return v;
}
static __device__ __forceinline__ f32x4 zero4() {
  f32x4 v = {0,0,0,0};
  return v;
}

// ---------------------------------------------------------------------------
// K0a: x fp32 -> xb bf16. grid 5120 x 256
// ---------------------------------------------------------------------------
__global__ __launch_bounds__(256) void cvt_x(const float* __restrict__ x,
                                             u16* __restrict__ xb) {
  const size_t i = (size_t)blockIdx.x * 256 + threadIdx.x;
  float4 v = *(const float4*)(x + i * 4);
  us4 o;
  o.x = f2b(v.x); o.y = f2b(v.y); o.z = f2b(v.z); o.w = f2b(v.w);
  *(us4*)(xb + i * 4) = o;
}

// ---------------------------------------------------------------------------
// K0b: Wq/Wk/Wv fp32 -> concat Wb[448][320] bf16. grid 140 x 256
// ---------------------------------------------------------------------------
__global__ __launch_bounds__(256) void cvt_w(const float* __restrict__ Wq,
                                             const float* __restrict__ Wk,
                                             const float* __restrict__ Wv,
                                             u16* __restrict__ Wb) {
  const int i = blockIdx.x * 256 + threadIdx.x;
  const int idx4 = i * 4;
  const int row = idx4 / CC;
  const int col = idx4 - row * CC;
  const float* src = (row < 64) ? (Wq + (size_t)row * CC)
                   : (row < 128) ? (Wk + (size_t)(row - 64) * CC)
                                 : (Wv + (size_t)(row - 128) * CC);
  float4 v = *(const float4*)(src + col);
  us4 o;
  o.x = f2b(v.x); o.y = f2b(v.y); o.z = f2b(v.z); o.w = f2b(v.w);
  *(us4*)(Wb + (size_t)row * CC + col) = o;
}

// ---------------------------------------------------------------------------
// K1: QKV GEMM. grid (7, 128). Blocks x=0: Q cols, x=1: K cols, x>=2: V cols.
// V results are written DIRECTLY transposed into Vt[b][c][n] using the fact
// that each C-fragment reg-group g holds 4 consecutive n values (packed us4).
// ---------------------------------------------------------------------------
__global__ __launch_bounds__(256) void gemm_qkv(
    const u16* __restrict__ xb, const u16* __restrict__ Wb,
    const float* __restrict__ bq, const float* __restrict__ bk,
    const float* __restrict__ bv,
    u16* __restrict__ Qb, u16* __restrict__ Kb, u16* __restrict__ Vt) {
  const int tid = threadIdx.x;
  const int lane = tid & 63, wid = tid >> 6;
  const int r = lane & 31, h = lane >> 5;
  const int m0 = blockIdx.y * 128 + wid * 32;
  const int col0 = blockIdx.x * 64;

  f32x16 acc0 = zero16(), acc1 = zero16();
  const u16* xrow = xb + (size_t)(m0 + r) * CC + h * 8;
  const u16* w0 = Wb + (size_t)(col0 + r) * CC + h * 8;
  const u16* w1 = w0 + 32 * CC;

  bf16x8 a   = *(const bf16x8*)(xrow);
  bf16x8 b0v = *(const bf16x8*)(w0);
  bf16x8 b1v = *(const bf16x8*)(w1);
#pragma unroll 1
  for (int ks = 0; ks < 20; ++ks) {
    bf16x8 na, nb0, nb1;
    if (ks < 19) {
      na  = *(const bf16x8*)(xrow + (ks + 1) * 16);
      nb0 = *(const bf16x8*)(w0 + (ks + 1) * 16);
      nb1 = *(const bf16x8*)(w1 + (ks + 1) * 16);
    }
    acc0 = __builtin_amdgcn_mfma_f32_32x32x16_bf16(a, b0v, acc0, 0, 0, 0);
    acc1 = __builtin_amdgcn_mfma_f32_32x32x16_bf16(a, b1v, acc1, 0, 0, 0);
    a = na; b0v = nb0; b1v = nb1;
  }

  const int bb = m0 >> 11;        // batch
  const int mloc = m0 & 2047;     // n within batch

#pragma unroll
  for (int nt = 0; nt < 2; ++nt) {
    const int col = col0 + nt * 32 + r;
    const f32x16 A = nt ? acc1 : acc0;
    if (col0 >= 128) {
      // V block: write transposed Vt[(bb*CC + c)][n], packed 4-n us4 stores
      const int c = col - 128;
      const float bias = bv[c];
      u16* vb = Vt + (((size_t)(bb * CC + c)) << 11) + mloc + 4 * h;
#pragma unroll
      for (int g = 0; g < 4; ++g) {
        us4 o;
#pragma unroll
        for (int e = 0; e < 4; ++e) o[e] = f2b(A[g * 4 + e] + bias);
        *(us4*)(vb + g * 8) = o;
      }
    } else if (col0 >= 64) {
      const float bias = bk[col - 64];
#pragma unroll
      for (int reg = 0; reg < 16; ++reg) {
        const int row = m0 + (reg & 3) + 8 * (reg >> 2) + 4 * h;
        Kb[(size_t)row * CQ + (col - 64)] = f2b(A[reg] + bias);
      }
    } else {
      const float bias = bq[col];
#pragma unroll
      for (int reg = 0; reg < 16; ++reg) {
        const int row = m0 + (reg & 3) + 8 * (reg >> 2) + 4 * h;
        Qb[(size_t)row * CQ + col] = f2b(A[reg] + bias);
      }
    }
  }
}

// ---------------------------------------------------------------------------
// K3: row sums with load prefetch. grid 256
// ---------------------------------------------------------------------------
__global__ __launch_bounds__(256) void row_stats(
    const u16* __restrict__ Qb, const u16* __restrict__ Kb,
    float* __restrict__ rowinv) {
  __shared__ float Sp[4][64];
  const int tid = threadIdx.x;
  const int lane = tid & 63, wid = tid >> 6;
  const int rl = lane & 15, hq = lane >> 4;
  const int bid = blockIdx.x;
  const int batch = bid & 7;
  const int r0g = batch * NN + (bid >> 3) * 64;

  bf16x8 af[4][2];
#pragma unroll
  for (int mt = 0; mt < 4; ++mt)
#pragma unroll
    for (int qs = 0; qs < 2; ++qs)
      af[mt][qs] = *(const bf16x8*)(Qb + (size_t)(r0g + mt * 16 + rl) * CQ + qs * 32 + hq * 8);

  float S[4][4];
#pragma unroll
  for (int mt = 0; mt < 4; ++mt)
#pragma unroll
    for (int rr = 0; rr < 4; ++rr) S[mt][rr] = 0.f;

  const int mstart = batch * NN + wid * 512;
  const u16* kr = Kb + (size_t)(mstart + rl) * CQ + hq * 8;
  bf16x8 c0 = *(const bf16x8*)(kr);
  bf16x8 c1 = *(const bf16x8*)(kr + 32);
#pragma unroll 1
  for (int ms = 0; ms < 32; ++ms) {
    bf16x8 n0, n1;
    if (ms < 31) {
      n0 = *(const bf16x8*)(kr + 16 * CQ);
      n1 = *(const bf16x8*)(kr + 16 * CQ + 32);
    }
#pragma unroll
    for (int mt = 0; mt < 4; ++mt) {
      f32x4 e = zero4();
      e = __builtin_amdgcn_mfma_f32_16x16x32_bf16(af[mt][0], c0, e, 0, 0, 0);
      e = __builtin_amdgcn_mfma_f32_16x16x32_bf16(af[mt][1], c1, e, 0, 0, 0);
#pragma unroll
      for (int rr = 0; rr < 4; ++rr) S[mt][rr] += __expf(e[rr] - 30.f);
    }
    c0 = n0; c1 = n1; kr += 16 * CQ;
  }

#pragma unroll
  for (int d = 1; d < 16; d <<= 1)
#pragma unroll
    for (int mt = 0; mt < 4; ++mt)
#pragma unroll
      for (int rr = 0; rr < 4; ++rr) S[mt][rr] += __shfl_xor(S[mt][rr], d, 64);

  if (rl == 0) {
#pragma unroll
    for (int mt = 0; mt < 4; ++mt)
#pragma unroll
      for (int rr = 0; rr < 4; ++rr) Sp[wid][mt * 16 + hq * 4 + rr] = S[mt][rr];
  }
  __syncthreads();
  if (tid < 64) {
    const float s = Sp[0][tid] + Sp[1][tid] + Sp[2][tid] + Sp[3][tid];
    rowinv[r0g + tid] = 1.0f / s;
  }
}

// ---------------------------------------------------------------------------
// K4: attention output v3.
// Block = 64n x 320c, 4 waves. Et: wave = quadrant (qn=wid>>1, qk=wid&1).
// PV: each wave owns FULL 64n (2 M-tiles) x c-tiles {wid, wid+4, wid+8<10}
// (waves 0,1: 3 tiles; waves 2,3: 2 tiles) -> no V-read redundancy.
// V read direct from L2-resident Vt into a register DOUBLE BUFFER, issued one
// full k-tile (~700cy) ahead to hide L2 latency. Pt in LDS double buffer.
// Residual uses xb (bf16). grid 256, batch = bid&7 pins to one XCD L2.
// ---------------------------------------------------------------------------
__global__ __launch_bounds__(256, 1) void attn(
    const u16* __restrict__ Qb, const u16* __restrict__ Kb,
    const u16* __restrict__ Vt, const float* __restrict__ rowinv,
    const u16* __restrict__ xb, const float* __restrict__ gamma,
    float* __restrict__ out) {
  __shared__ __align__(16) u16 PtU[2][64 * 64];
  const int tid = threadIdx.x;
  const int lane = tid & 63, wid = tid >> 6;
  const int qn = wid >> 1, qk = wid & 1;   // Et quadrant
  const int r = lane & 31, h = lane >> 5;
  const int b = blockIdx.x & 7;
  const int n0 = (blockIdx.x >> 3) * 64;
  const int NT = (wid < 2) ? 3 : 2;        // PV c-tiles this wave owns

  // held A-frags for Et: K rows of quadrant qn
  bf16x8 kf[4];
  {
    const u16* krow = Kb + (size_t)(b * NN + n0 + qn * 32 + r) * CQ + h * 8;
#pragma unroll
    for (int qs = 0; qs < 4; ++qs) kf[qs] = *(const bf16x8*)(krow + qs * 16);
  }

  f32x16 acc[2][3];
#pragma unroll
  for (int m = 0; m < 2; ++m)
#pragma unroll
    for (int j = 0; j < 3; ++j) acc[m][j] = zero16();

  const u16* qbase = Qb + (size_t)(b * NN + qk * 32 + r) * CQ + h * 8;
  const float* rbase = rowinv + b * NN + qk * 32 + r;
  const int kk = qk * 32 + r;
  char* Pt0 = (char*)&PtU[0][0];

  const u16* vbase[3];
#pragma unroll
  for (int j = 0; j < 3; ++j) {
    const int ct = (j < NT) ? (wid + j * 4) : wid;   // clamp to stay in-bounds
    vbase[j] = Vt + (((size_t)(b * CC + ct * 32 + r)) << 11) + h * 8;
  }

  bf16x8 vA[3][4], vB[3][4];

#define LOADV(T, VB) do {                                                      \
    const int k0_ = (T) * 64;                                                  \
    _Pragma("unroll")                                                          \
    for (int j = 0; j < 3; ++j) if (j < NT) {                                  \
      _Pragma("unroll")                                                        \
      for (int ks = 0; ks < 4; ++ks)                                           \
        VB[j][ks] = *(const bf16x8*)(vbase[j] + k0_ + ks * 16);                \
    }                                                                          \
  } while (0)

#define ET_STEP(T, BUF) do {                                                   \
    const int k0_ = (T) * 64;                                                  \
    f32x16 e_ = zero16();                                                      \
    const u16* q0_ = qbase + (size_t)k0_ * CQ;                                 \
    _Pragma("unroll")                                                          \
    for (int qs = 0; qs < 4; ++qs) {                                           \
      bf16x8 qf_ = *(const bf16x8*)(q0_ + qs * 16);                            \
      e_ = __builtin_amdgcn_mfma_f32_32x32x16_bf16(kf[qs], qf_, e_, 0, 0, 0);  \
    }                                                                          \
    const float inv_ = rbase[k0_];                                             \
    _Pragma("unroll")                                                          \
    for (int reg = 0; reg < 16; ++reg) {                                       \
      const int nl_ = qn * 32 + (reg & 3) + 8 * (reg >> 2) + 4 * h;            \
      const float p_ = __expf(e_[reg] - 30.f) * inv_;                          \
      *(u16*)(Pt0 + (BUF) * 8192 + nl_ * 128 +                                 \
              ((((kk >> 3) ^ (nl_ & 7)) << 4)) + (kk & 7) * 2) = f2b(p_);      \
    }                                                                          \
  } while (0)

#define PV_STEP(BUF, VB) do {                                                  \
    _Pragma("unroll")                                                          \
    for (int ks = 0; ks < 4; ++ks) {                                           \
      const int ch_ = ks * 2 + h;                                              \
      bf16x8 pa0 = *(const bf16x8*)(Pt0 + (BUF) * 8192 + r * 128 +             \
                                    ((ch_ ^ (r & 7)) << 4));                   \
      bf16x8 pa1 = *(const bf16x8*)(Pt0 + (BUF) * 8192 + (32 + r) * 128 +      \
                                    ((ch_ ^ (r & 7)) << 4));                   \
      _Pragma("unroll")                                                        \
      for (int j = 0; j < 3; ++j) if (j < NT) {                                \
        acc[0][j] = __builtin_amdgcn_mfma_f32_32x32x16_bf16(pa0, VB[j][ks], acc[0][j], 0, 0, 0); \
        acc[1][j] = __builtin_amdgcn_mfma_f32_32x32x16_bf16(pa1, VB[j][ks], acc[1][j], 0, 0, 0); \
      }                                                                        \
    }                                                                          \
  } while (0)

  LOADV(0, vA);
  ET_STEP(0, 0);
  __syncthreads();
#pragma unroll 1
  for (int tt = 0; tt < 15; ++tt) {
    LOADV(2 * tt + 1, vB);
    ET_STEP(2 * tt + 1, 1);
    PV_STEP(0, vA);               // tile 2tt
    __syncthreads();
    LOADV(2 * tt + 2, vA);
    ET_STEP(2 * tt + 2, 0);
    PV_STEP(1, vB);               // tile 2tt+1
    __syncthreads();
  }
  // tail: tiles 30, 31
  LOADV(31, vB);
  ET_STEP(31, 1);
  PV_STEP(0, vA);                 // tile 30
  __syncthreads();
  PV_STEP(1, vB);                 // tile 31

#undef LOADV
#undef ET_STEP
#undef PV_STEP

  const float g = gamma[0];
#pragma unroll
  for (int m = 0; m < 2; ++m) {
#pragma unroll
    for (int reg = 0; reg < 16; ++reg) {
      const int nl = n0 + m * 32 + (reg & 3) + 8 * (reg >> 2) + 4 * h;
      const size_t rowb = ((size_t)(b * NN) + nl) * CC;
#pragma unroll
      for (int j = 0; j < 3; ++j) if (j < NT) {
        const size_t idx = rowb + (size_t)((wid + j * 4) * 32 + r);
        out[idx] = g * acc[m][j][reg] + b2f(xb[idx]);
      }
    }
  }
}

extern "C" void kernel_launch(void* const* d_in, const int* in_sizes, int n_in,
                              void* d_out, int out_size, void* d_ws, size_t ws_size,
                              hipStream_t stream) {
  const float* x     = (const float*)d_in[0];
  const float* Wq    = (const float*)d_in[1];
  const float* bq    = (const float*)d_in[2];
  const float* Wk    = (const float*)d_in[3];
  const float* bk    = (const float*)d_in[4];
  const float* Wv    = (const float*)d_in[5];
  const float* bv    = (const float*)d_in[6];
  const float* gamma = (const float*)d_in[7];
  float* out = (float*)d_out;

  char* w = (char*)d_ws;
  u16* xb     = (u16*)(w);                         // 16384*320  (10485760 B)
  u16* Wb     = (u16*)(w + 10485760);              // 448*320    (286720 B)
  u16* Qb     = (u16*)(w + 10772480);              // 16384*64   (2097152 B)
  u16* Kb     = (u16*)(w + 12869632);              // 16384*64   (2097152 B)
  u16* Vt     = (u16*)(w + 14966784);              // 8*320*2048 (10485760 B)
  float* rinv = (float*)(w + 25452544);            // 16384      (65536 B)

  cvt_x<<<5120, 256, 0, stream>>>(x, xb);
  cvt_w<<<140, 256, 0, stream>>>(Wq, Wk, Wv, Wb);
  gemm_qkv<<<dim3(7, 128), 256, 0, stream>>>(xb, Wb, bq, bk, bv, Qb, Kb, Vt);
  row_stats<<<256, 256, 0, stream>>>(Qb, Kb, rinv);
  attn<<<256, 256, 0, stream>>>(Qb, Kb, Vt, rinv, xb, gamma, out);
}